// Round 2
// baseline (72.412 us; speedup 1.0000x reference)
//
#include <hip/hip_runtime.h>
#include <hip/hip_bf16.h>

namespace {

constexpr int kB = 4, kF = 64, kN = 4096;
constexpr int kM = kB * kF * kN;  // 1048576 total elements for std()

typedef __attribute__((ext_vector_type(8))) short bf16x8;
typedef __attribute__((ext_vector_type(4))) float f32x4;

__device__ __forceinline__ void wave_red2(float& s, float& q) {
#pragma unroll
  for (int o = 32; o > 0; o >>= 1) {
    s += __shfl_down(s, o, 64);
    q += __shfl_down(q, o, 64);
  }
}

// K1: 1024 blocks x 256 threads, each thread reduces 4 floats (float4 load).
__global__ void k_reduce1(const float* __restrict__ emb, float* __restrict__ part) {
  int t = blockIdx.x * blockDim.x + threadIdx.x;
  float4 v = reinterpret_cast<const float4*>(emb)[t];
  float s = v.x + v.y + v.z + v.w;
  float q = v.x * v.x + v.y * v.y + v.z * v.z + v.w * v.w;
  wave_red2(s, q);
  __shared__ float ls[4], lq[4];
  int lane = threadIdx.x & 63, w = threadIdx.x >> 6;
  if (lane == 0) { ls[w] = s; lq[w] = q; }
  __syncthreads();
  if (threadIdx.x == 0) {
    s = ls[0] + ls[1] + ls[2] + ls[3];
    q = lq[0] + lq[1] + lq[2] + lq[3];
    part[blockIdx.x] = s;
    part[1024 + blockIdx.x] = q;
  }
}

// K2: single block of 1024 threads folds the partials, writes inv_std to part[2048].
__global__ void k_reduce2(float* __restrict__ part) {
  int t = threadIdx.x;
  float s = part[t], q = part[1024 + t];
  wave_red2(s, q);
  __shared__ float ls[16], lq[16];
  int lane = t & 63, w = t >> 6;
  if (lane == 0) { ls[w] = s; lq[w] = q; }
  __syncthreads();
  if (t == 0) {
    s = 0.f; q = 0.f;
#pragma unroll
    for (int i = 0; i < 16; i++) { s += ls[i]; q += lq[i]; }
    float mean = s / (float)kM;
    float var = (q - s * mean) / (float)(kM - 1);  // Bessel ddof=1
    part[2048] = 1.0f / sqrtf(var);
  }
}

// K3: coordT[b][n][f] = bf16(emb[b][f][n] * inv_std); sq[b][n] = sum_f coord^2
// (sq computed from the ROUNDED bf16 values so the diagonal of d2 is exactly 0).
__global__ void k_convert(const float* __restrict__ emb, const float* __restrict__ part,
                          unsigned short* __restrict__ coordT, float* __restrict__ sq) {
  float inv_std = part[2048];
  int g = blockIdx.x * blockDim.x + threadIdx.x;  // [0, B*N)
  int b = g >> 12;
  int n = g & 4095;
  const float* src = emb + ((size_t)b * kF) * kN + n;
  alignas(16) unsigned short loc[kF];
  float acc = 0.f;
#pragma unroll
  for (int f = 0; f < kF; f++) {
    float v = src[(size_t)f * kN] * inv_std;  // coalesced across threads (stride over f)
    union { __hip_bfloat16 h; unsigned short u; } cv;
    cv.h = __float2bfloat16(v);
    loc[f] = cv.u;
    float vf = __bfloat162float(cv.h);
    acc += vf * vf;
  }
  unsigned short* dst = coordT + (size_t)g * kF;
#pragma unroll
  for (int i = 0; i < kF / 8; i++)
    reinterpret_cast<bf16x8*>(dst)[i] = reinterpret_cast<const bf16x8*>(loc)[i];
  sq[g] = acc;
}

// K4: per batch, out = exp(-max((sq_i + sq_j - 2*coordT·coordT^T),0)/64/2).
// 256 threads = 4 waves; each wave owns a 64x64 output tile (block: 128x128).
// coordT (2 MB) is L2/L3-resident -> fragments loaded straight from global.
__global__ __launch_bounds__(256, 1) void k_gemm_exp(const unsigned short* __restrict__ coordT,
                                                     const float* __restrict__ sq,
                                                     float* __restrict__ out) {
  int b = blockIdx.z;
  int wid = threadIdx.x >> 6;
  int lane = threadIdx.x & 63;
  int lhi = lane >> 4, llo = lane & 15;
  int i0 = blockIdx.y * 128 + (wid >> 1) * 64;
  int j0 = blockIdx.x * 128 + (wid & 1) * 64;
  const unsigned short* base = coordT + (size_t)b * kN * kF;

  // A fragment: lane holds row (i0+m*16+llo), k = kk*32 + lhi*8 .. +7  (contig short8)
  bf16x8 af[4][2], bfr[4][2];
#pragma unroll
  for (int m = 0; m < 4; m++) {
    const unsigned short* p = base + (size_t)(i0 + m * 16 + llo) * kF + lhi * 8;
    af[m][0] = *reinterpret_cast<const bf16x8*>(p);
    af[m][1] = *reinterpret_cast<const bf16x8*>(p + 32);
  }
#pragma unroll
  for (int n = 0; n < 4; n++) {
    const unsigned short* p = base + (size_t)(j0 + n * 16 + llo) * kF + lhi * 8;
    bfr[n][0] = *reinterpret_cast<const bf16x8*>(p);
    bfr[n][1] = *reinterpret_cast<const bf16x8*>(p + 32);
  }

  f32x4 acc[4][4] = {};
#pragma unroll
  for (int kk = 0; kk < 2; kk++)
#pragma unroll
    for (int m = 0; m < 4; m++)
#pragma unroll
      for (int n = 0; n < 4; n++)
        acc[m][n] = __builtin_amdgcn_mfma_f32_16x16x32_bf16(af[m][kk], bfr[n][kk], acc[m][n], 0, 0, 0);

  const float* sqb = sq + (size_t)b * kN;
  float si[4][4];
#pragma unroll
  for (int m = 0; m < 4; m++) {
    float4 t = *reinterpret_cast<const float4*>(&sqb[i0 + m * 16 + lhi * 4]);
    si[m][0] = t.x; si[m][1] = t.y; si[m][2] = t.z; si[m][3] = t.w;
  }
  float sj[4];
#pragma unroll
  for (int n = 0; n < 4; n++) sj[n] = sqb[j0 + n * 16 + llo];

  float* ob = out + (size_t)b * kN * kN;
#pragma unroll
  for (int m = 0; m < 4; m++) {
#pragma unroll
    for (int n = 0; n < 4; n++) {
#pragma unroll
      for (int r = 0; r < 4; r++) {
        // C/D layout (HW-verified): col = lane&15, row = (lane>>4)*4 + r
        int i = i0 + m * 16 + lhi * 4 + r;
        int j = j0 + n * 16 + llo;
        float d2 = (si[m][r] + sj[n] - 2.0f * acc[m][n][r]) * (1.0f / 64.0f);
        d2 = fmaxf(d2, 0.0f);
        ob[(size_t)i * kN + j] = __expf(-0.5f * d2);
      }
    }
  }
}

}  // namespace

extern "C" void kernel_launch(void* const* d_in, const int* in_sizes, int n_in,
                              void* d_out, int out_size, void* d_ws, size_t ws_size,
                              hipStream_t stream) {
  const float* emb = (const float*)d_in[1];  // d_in[0] = adj_in (unused by reference)
  float* out = (float*)d_out;

  // ws layout: [0, 8196B) reduction partials + inv_std; coordT @16KB (2 MB); sq after.
  float* part = (float*)d_ws;
  unsigned short* coordT = (unsigned short*)((char*)d_ws + 16384);
  float* sq = (float*)((char*)d_ws + 16384 + (size_t)kB * kN * kF * sizeof(unsigned short));

  k_reduce1<<<1024, 256, 0, stream>>>(emb, part);
  k_reduce2<<<1, 1024, 0, stream>>>(part);
  k_convert<<<(kB * kN) / 256, 256, 0, stream>>>(emb, part, coordT, sq);
  dim3 grid(kN / 128, kN / 128, kB);
  k_gemm_exp<<<grid, 256, 0, stream>>>(coordT, sq, out);
}